// Round 5
// baseline (119.786 us; speedup 1.0000x reference)
//
#include <hip/hip_runtime.h>
#include <math.h>

// Problem constants (from reference)
#define NSAMP 16
#define NPTS  512
#define MDIM  4096     // 64*64 grid
#define NIT   100

// 16x16 window (rows rn-7..rn+8, cols cn-7..cn+8), 4 cells/lane for a wave.
// Support analysis (R4-R12-validated): first-visit pits displace the softmax
// mode ~3 cells; rim + mass tail needs +-6 cells -> 16x16 minimum safe.
#define R0MAX 48

// No-max softmax safety (R12-validated): z = v - 0.1*d^2 < 0 always and
// S >= e^-28 -> unshifted __expf neither overflows nor underflows S.

// parity swizzle: odd rows XOR col by 16 -> ~2 lanes/bank (R7: 75k -> 2k).
__device__ __forceinline__ int swz(int r, int c) {
  return r * 64 + (c ^ ((r & 1) << 4));
}

// ---------------- Threefry-2x32 (JAX-exact, partitionable path; R0-verified)
__device__ __forceinline__ void tf2x32(unsigned k0, unsigned k1,
                                       unsigned c0, unsigned c1,
                                       unsigned &o0, unsigned &o1)
{
  unsigned ks2 = k0 ^ k1 ^ 0x1BD11BDAu;
  unsigned x0 = c0 + k0, x1 = c1 + k1;
#define ROT(r) x0 += x1; x1 = (x1 << (r)) | (x1 >> (32 - (r))); x1 ^= x0;
#define G0 ROT(13) ROT(15) ROT(26) ROT(6)
#define G1 ROT(17) ROT(29) ROT(16) ROT(24)
  G0 x0 += k1;  x1 += ks2 + 1u;
  G1 x0 += ks2; x1 += k0  + 2u;
  G0 x0 += k0;  x1 += k1  + 3u;
  G1 x0 += k1;  x1 += ks2 + 4u;
  G0 x0 += ks2; x1 += k0  + 5u;
#undef G0
#undef G1
#undef ROT
  o0 = x0; o1 = x1;
}

__device__ __forceinline__ int rand_idx(int f)
{
  unsigned ka, kb, w0, w1;
  tf2x32(0u, 1u, 0u, 1u, ka, kb);            // split(key(1))[1] — folded
  tf2x32(ka, kb, 0u, (unsigned)f, w0, w1);   // random_bits elem f
  return (int)((w0 ^ w1) & 511u);
}

// ---------------- wave64 sum via DPP (R1-R12-verified pattern) --------------
template<int CTRL>
__device__ __forceinline__ float dpp_mv(float v, float id)
{
  return __int_as_float(__builtin_amdgcn_update_dpp(
      __float_as_int(id), __float_as_int(v), CTRL, 0xF, 0xF, false));
}

__device__ __forceinline__ float waveSum(float v)
{
  v += dpp_mv<0x111>(v, 0.0f);
  v += dpp_mv<0x112>(v, 0.0f);
  v += dpp_mv<0x114>(v, 0.0f);
  v += dpp_mv<0x118>(v, 0.0f);
  v += dpp_mv<0x142>(v, 0.0f);
  v += dpp_mv<0x143>(v, 0.0f);
  return __int_as_float(__builtin_amdgcn_readlane(__float_as_int(v), 63));
}

// ---------------- R18: single dispatch, producer/consumer blocks ------------
// Blocks 0..15: producer (R17 kern_scan, bit-identical) -> w[] to global,
//   then device-scope release of flag[s].
// Blocks 16..143: consumer (R17 kern_wd, bit-identical math); spin-acquire
//   flag[s], fence, stage w, compute wd slice.
// Deadlock-safety: 144 blocks x 1024 thr, ~68 KB LDS -> >=2 blocks/CU on
// 256 CUs => all blocks co-resident under ANY dispatch order; consumers
// never gate producers. Flags live in d_ws (poisoned) -> zeroed by a
// 64-byte memsetAsync before launch.
__global__ __launch_bounds__(1024) void kern_all(
    const float *__restrict__ normed, const float *__restrict__ pts,
    float *__restrict__ out, float *__restrict__ wglob,
    unsigned *__restrict__ flags)
{
  const int t = threadIdx.x;
  const int v = t >> 6;            // wave 0..15
  const int L = t & 63;
  const int rbase = L >> 4;        // 0..3 (window row within quad)
  const int cbase = L & 15;        // window col

  __shared__ float2 dav[MDIM];     // 32 KB: (D, avacc), swizzled (producer)
  __shared__ float  barr[MDIM];    // 16 KB: b (producer) / w-staging (consumer)
  __shared__ float4 cstA[NIT + 4]; // (ux, uy, step1, Pk) per iter
  __shared__ int2   cstB[NIT + 4]; // (r0, c0) per iter
  __shared__ float  spfin;         // exact sum of Pk, k ascending
  __shared__ float2 pts2[64];      // consumer: slice points
  __shared__ float  red[16];

  if (blockIdx.x < NSAMP) {
    // =================== PRODUCER: scan + epilogue -> w[] ===================
    const int s = blockIdx.x;

    // ---- init (all 16 waves; wave v owns grid rows 4v..4v+3) ----
    #pragma unroll
    for (int l = 0; l < 4; ++l) {
      const int r = 4 * v + l;
      const float bv = normed[s * MDIM + r * 64 + L];
      const int idx = swz(r, L);
      dav[idx]  = make_float2(__logf(bv), 0.0f);   // v0 = lnb
      barr[idx] = bv;
    }
    // per-iteration constants (bit-identical formulas, hoisted)
    if (t < NIT + 4) {
      const int kk = t < NIT ? t : (NIT - 1);
      const int idx = rand_idx(s * NIT + kk);
      const float2 p = ((const float2 *)pts)[s * NPTS + idx];
      const int rn = (int)floorf((p.y - 4.0f) * 0.125f + 0.5f);
      const int cn = (int)floorf((p.x - 4.0f) * 0.125f + 0.5f);
      int r0 = rn - 7; r0 = r0 < 0 ? 0 : (r0 > R0MAX ? R0MAX : r0);
      int c0 = cn - 7; c0 = c0 < 0 ? 0 : (c0 > R0MAX ? R0MAX : c0);
      const float kf    = (float)(kk + 1);
      const float step1 = 512.0f * __builtin_amdgcn_rsqf(kf); // 0.1*lr/sqrt(k)
      const float Pk    = step1 * (0.01f * (101.0f - kf));
      cstA[t] = make_float4(p.x - (float)(8 * c0 + 4),
                            p.y - (float)(8 * r0 + 4), step1, Pk);
      cstB[t] = make_int2(r0, c0);
    }
    __syncthreads();

    const float fc8 = (float)(8 * cbase);
    const float fr8 = (float)(8 * rbase);

    // ---- phase 1: 100-iter ASGD scan, wave 0 only (R13-exact body) ----
    if (t == 64) {
      float SPa = 0.0f;
      for (int k = 0; k < NIT; ++k) SPa += cstA[k].w;
      spfin = SPa;
    }
    if (v == 0) {
      float A = 0.0f;
      float4 cA = cstA[0];
      int2   cB = cstB[0];
      int j0 = swz(cB.x + rbase, cB.y + cbase);
      float2 c0v = dav[j0      ]; float b0v = barr[j0      ];
      float2 c1v = dav[j0 + 256]; float b1v = barr[j0 + 256];
      float2 c2v = dav[j0 + 512]; float b2v = barr[j0 + 512];
      float2 c3v = dav[j0 + 768]; float b3v = barr[j0 + 768];

      for (int k = 0; k < NIT; ++k) {
        const float4 cAn = cstA[k + 1];
        const int2   cBn = cstB[k + 1];

        const float dx  = cA.x - fc8;       // x - (8*(c0+cbase)+4)
        const float dxx = dx * dx;
        const float ty  = cA.y - fr8;       // dy_q = ty - 32q
        // unshifted exp: z < 0 always (R12-validated) -> no max reduction
        const float e0 = __expf(fmaf(fmaf(ty,          ty,          dxx), -0.1f, fmaf(b0v, A, c0v.x)));
        const float e1 = __expf(fmaf(fmaf(ty - 32.0f, ty - 32.0f, dxx), -0.1f, fmaf(b1v, A, c1v.x)));
        const float e2 = __expf(fmaf(fmaf(ty - 64.0f, ty - 64.0f, dxx), -0.1f, fmaf(b2v, A, c2v.x)));
        const float e3 = __expf(fmaf(fmaf(ty - 96.0f, ty - 96.0f, dxx), -0.1f, fmaf(b3v, A, c3v.x)));

        const float S    = waveSum((e0 + e1) + (e2 + e3));   // > 0
        const float invS = __builtin_amdgcn_rcpf(S);
        const float cD = cA.z * invS, cAv = cA.w * invS;

        c0v.x = fmaf(-cD, e0, c0v.x); c0v.y = fmaf(cAv, e0, c0v.y);
        c1v.x = fmaf(-cD, e1, c1v.x); c1v.y = fmaf(cAv, e1, c1v.y);
        c2v.x = fmaf(-cD, e2, c2v.x); c2v.y = fmaf(cAv, e2, c2v.y);
        c3v.x = fmaf(-cD, e3, c3v.x); c3v.y = fmaf(cAv, e3, c3v.y);
        dav[j0      ] = c0v;
        dav[j0 + 256] = c1v;
        dav[j0 + 512] = c2v;
        dav[j0 + 768] = c3v;

        A += cA.z;

        // rotate + issue next-iter state reads AFTER the writes (same-wave
        // DS ordering guarantees RAW; latency overlaps loop-back + z-prep)
        cA = cAn; cB = cBn;
        j0 = swz(cB.x + rbase, cB.y + cbase);
        c0v = dav[j0      ]; b0v = barr[j0      ];
        c1v = dav[j0 + 256]; b1v = barr[j0 + 256];
        c2v = dav[j0 + 512]; b2v = barr[j0 + 512];
        c3v = dav[j0 + 768]; b3v = barr[j0 + 768];
      }
    }
    __syncthreads();                               // dav final; spfin ready

    // ---- epilogue (ALL 16 waves, own slab): w[] -> global; ot partials ----
    {
      const float SP = spfin;
      float p_ot = 0.0f;
      #pragma unroll
      for (int l = 0; l < 4; ++l) {
        const int r   = 4 * v + l;
        const int idx = swz(r, L);
        const float2 cd = dav[idx];
        const float bb  = barr[idx];
        const float tt  = fmaf(bb, SP, -cd.y);     // 0.1*beta
        wglob[s * MDIM + r * 64 + L] = tt + __logf(bb);  // w = 0.1*beta + lnb
        p_ot = fmaf(bb, 10.0f * tt, p_ot);
      }
      p_ot = waveSum(p_ot);
      if (L == 0) red[v] = p_ot;
    }
    __syncthreads();                 // all w-stores issued + drained (barrier
                                     // implies vmcnt(0)); red[] complete
    if (t == 0) {
      float ot = 0.0f;
      #pragma unroll
      for (int i = 0; i < 16; ++i) ot += red[i];
      atomicAdd(&out[2], ot);
      __threadfence();               // device-scope release of w-stores
      __hip_atomic_store(&flags[s], 1u, __ATOMIC_RELEASE,
                         __HIP_MEMORY_SCOPE_AGENT);
      // out[0] (loss): analytically exact 0; memset provides it.
    }
  } else {
    // =================== CONSUMER: windowed per-point wd ====================
    const int cb = blockIdx.x - NSAMP;
    const int s = cb >> 3;
    const int q = cb & 7;

    if (t < 64) pts2[t] = ((const float2 *)pts)[s * NPTS + 64 * q + t];

    // acquire this sample's w[] (thread 0 spins; never gates any producer)
    if (t == 0) {
      while (__hip_atomic_load(&flags[s], __ATOMIC_ACQUIRE,
                               __HIP_MEMORY_SCOPE_AGENT) == 0u) {
        __builtin_amdgcn_s_sleep(8);
      }
    }
    __syncthreads();                 // flag seen; pts2 staged
    __threadfence();                 // agent-scope acquire in every thread

    // stage w with the producer's parity swizzle (conflict-free window reads)
    #pragma unroll
    for (int l = 0; l < 4; ++l) {
      const int r = 4 * v + l;
      barr[swz(r, L)] = wglob[s * MDIM + r * 64 + L];
    }
    __syncthreads();

    float pe[4], pq[4];
    #pragma unroll
    for (int i = 0; i < 4; ++i) {
      const int p = 4 * v + i;                   // point within slice
      const float2 pt = pts2[p];                 // LDS broadcast
      const float x = pt.x, y = pt.y;
      const int rn = (int)floorf((y - 4.0f) * 0.125f + 0.5f);
      const int cn = (int)floorf((x - 4.0f) * 0.125f + 0.5f);
      int r0 = rn - 7; r0 = r0 < 0 ? 0 : (r0 > R0MAX ? R0MAX : r0);
      int c0 = cn - 7; c0 = c0 < 0 ? 0 : (c0 > R0MAX ? R0MAX : c0);
      const int rl = r0 + rbase;
      const int cl = c0 + cbase;
      const int j0 = swz(rl, cl);

      const float dx  = x - (float)(8 * cl + 4);
      const float dxx = dx * dx;
      const float ty  = y - (float)(8 * rl + 4);
      float spe = 0.0f, spq = 0.0f;
      #pragma unroll
      for (int qq4 = 0; qq4 < 4; ++qq4) {
        const float wv = barr[j0 + 256 * qq4];
        const float dy = ty - (float)(32 * qq4);
        const float qq = fmaf(dy, dy, dxx);
        const float e  = __expf(fmaf(qq, -0.1f, wv));
        spe += e;
        spq = fmaf(e, qq, spq);
      }
      pe[i] = spe; pq[i] = spq;
    }
    // 8 interleaved DPP sum chains
    #pragma unroll
    for (int i = 0; i < 4; ++i) { pe[i] += dpp_mv<0x111>(pe[i], 0.0f); pq[i] += dpp_mv<0x111>(pq[i], 0.0f); }
    #pragma unroll
    for (int i = 0; i < 4; ++i) { pe[i] += dpp_mv<0x112>(pe[i], 0.0f); pq[i] += dpp_mv<0x112>(pq[i], 0.0f); }
    #pragma unroll
    for (int i = 0; i < 4; ++i) { pe[i] += dpp_mv<0x114>(pe[i], 0.0f); pq[i] += dpp_mv<0x114>(pq[i], 0.0f); }
    #pragma unroll
    for (int i = 0; i < 4; ++i) { pe[i] += dpp_mv<0x118>(pe[i], 0.0f); pq[i] += dpp_mv<0x118>(pq[i], 0.0f); }
    #pragma unroll
    for (int i = 0; i < 4; ++i) { pe[i] += dpp_mv<0x142>(pe[i], 0.0f); pq[i] += dpp_mv<0x142>(pq[i], 0.0f); }
    #pragma unroll
    for (int i = 0; i < 4; ++i) { pe[i] += dpp_mv<0x143>(pe[i], 0.0f); pq[i] += dpp_mv<0x143>(pq[i], 0.0f); }

    float wdacc = 0.0f;
    #pragma unroll
    for (int i = 0; i < 4; ++i) {
      const float PE = __int_as_float(__builtin_amdgcn_readlane(__float_as_int(pe[i]), 63));
      const float PQ = __int_as_float(__builtin_amdgcn_readlane(__float_as_int(pq[i]), 63));
      wdacc = fmaf(PQ, __builtin_amdgcn_rcpf(PE), wdacc);
    }
    if (L == 0) red[v] = wdacc;
    __syncthreads();
    if (t == 0) {
      float wd = 0.0f;
      #pragma unroll
      for (int i = 0; i < 16; ++i) wd += red[i];
      atomicAdd(&out[1], wd * (1.0f / 512.0f));
    }
  }
}

extern "C" void kernel_launch(void* const* d_in, const int* in_sizes, int n_in,
                              void* d_out, int out_size, void* d_ws, size_t ws_size,
                              hipStream_t stream)
{
  (void)in_sizes; (void)n_in; (void)out_size; (void)ws_size;
  const float *normed = (const float *)d_in[0];
  const float *pts    = (const float *)d_in[2];
  float *out      = (float *)d_out;
  float *wglob    = (float *)d_ws;                       // 256 KiB
  unsigned *flags = (unsigned *)((char *)d_ws + NSAMP * MDIM * sizeof(float));

  hipMemsetAsync(out, 0, 3 * sizeof(float), stream);
  hipMemsetAsync(flags, 0, NSAMP * sizeof(unsigned), stream);  // d_ws poisoned
  kern_all<<<dim3(NSAMP + NSAMP * 8), dim3(1024), 0, stream>>>(
      normed, pts, out, wglob, flags);
}

// Round 6
// 86.137 us; speedup vs baseline: 1.3906x; 1.3906x over previous
//
#include <hip/hip_runtime.h>
#include <math.h>

// Problem constants (from reference)
#define NSAMP 16
#define NPTS  512
#define MDIM  4096     // 64*64 grid
#define NIT   100

// 16x16 window (rows rn-7..rn+8, cols cn-7..cn+8), 4 cells/lane for a wave.
// Support analysis (R4-R12-validated): first-visit pits displace the softmax
// mode ~3 cells; rim + mass tail needs +-6 cells -> 16x16 minimum safe.
#define R0MAX 48

// No-max softmax safety (R12-validated): z = v - 0.1*d^2 < 0 always and
// S >= e^-28 -> unshifted __expf neither overflows nor underflows S.

// parity swizzle: odd rows XOR col by 16 -> ~2 lanes/bank (R7: 75k -> 2k).
__device__ __forceinline__ int swz(int r, int c) {
  return r * 64 + (c ^ ((r & 1) << 4));
}

// ---------------- Threefry-2x32 (JAX-exact, partitionable path; R0-verified)
__device__ __forceinline__ void tf2x32(unsigned k0, unsigned k1,
                                       unsigned c0, unsigned c1,
                                       unsigned &o0, unsigned &o1)
{
  unsigned ks2 = k0 ^ k1 ^ 0x1BD11BDAu;
  unsigned x0 = c0 + k0, x1 = c1 + k1;
#define ROT(r) x0 += x1; x1 = (x1 << (r)) | (x1 >> (32 - (r))); x1 ^= x0;
#define G0 ROT(13) ROT(15) ROT(26) ROT(6)
#define G1 ROT(17) ROT(29) ROT(16) ROT(24)
  G0 x0 += k1;  x1 += ks2 + 1u;
  G1 x0 += ks2; x1 += k0  + 2u;
  G0 x0 += k0;  x1 += k1  + 3u;
  G1 x0 += k1;  x1 += ks2 + 4u;
  G0 x0 += ks2; x1 += k0  + 5u;
#undef G0
#undef G1
#undef ROT
  o0 = x0; o1 = x1;
}

__device__ __forceinline__ int rand_idx(int f)
{
  unsigned ka, kb, w0, w1;
  tf2x32(0u, 1u, 0u, 1u, ka, kb);            // split(key(1))[1] — folded
  tf2x32(ka, kb, 0u, (unsigned)f, w0, w1);   // random_bits elem f
  return (int)((w0 ^ w1) & 511u);
}

// ---------------- wave64 sum via DPP (R1-R12-verified pattern) --------------
template<int CTRL>
__device__ __forceinline__ float dpp_mv(float v, float id)
{
  return __int_as_float(__builtin_amdgcn_update_dpp(
      __float_as_int(id), __float_as_int(v), CTRL, 0xF, 0xF, false));
}

__device__ __forceinline__ float waveSum(float v)
{
  v += dpp_mv<0x111>(v, 0.0f);
  v += dpp_mv<0x112>(v, 0.0f);
  v += dpp_mv<0x114>(v, 0.0f);
  v += dpp_mv<0x118>(v, 0.0f);
  v += dpp_mv<0x142>(v, 0.0f);
  v += dpp_mv<0x143>(v, 0.0f);
  return __int_as_float(__builtin_amdgcn_readlane(__float_as_int(v), 63));
}

// two interleaved wave sums: each chain's add tree is IDENTICAL to waveSum
// (bit-exact); the two chains overlap via ILP -> ~1.2x one chain's latency.
__device__ __forceinline__ void waveSum2(float &a, float &b)
{
  a += dpp_mv<0x111>(a, 0.0f); b += dpp_mv<0x111>(b, 0.0f);
  a += dpp_mv<0x112>(a, 0.0f); b += dpp_mv<0x112>(b, 0.0f);
  a += dpp_mv<0x114>(a, 0.0f); b += dpp_mv<0x114>(b, 0.0f);
  a += dpp_mv<0x118>(a, 0.0f); b += dpp_mv<0x118>(b, 0.0f);
  a += dpp_mv<0x142>(a, 0.0f); b += dpp_mv<0x142>(b, 0.0f);
  a += dpp_mv<0x143>(a, 0.0f); b += dpp_mv<0x143>(b, 0.0f);
  a = __int_as_float(__builtin_amdgcn_readlane(__float_as_int(a), 63));
  b = __int_as_float(__builtin_amdgcn_readlane(__float_as_int(b), 63));
}

// ---------------- Kernel 1: paired scan + epilogue -> w[] -------------------
// R19 = R17 (two dispatches; R18 single-dispatch fusion REVERTED: merged
// regalloc spilled the scan loop, 24 VGPR + scratch -> 63 us) with phase 1
// processing FIXED PAIRS of iterations per wave-step. Disjoint pair (~55%):
// both iterations' chains (exp -> 6-DPP reduce -> rcp -> update) are data-
// independent (A is an exact scalar prefix) and interleave via ILP in one
// wave -> ~1.2x one chain for two iterations. Overlapping pair: two
// sequential R13 bodies (window kp+1 re-read after kp's writes). Next pair
// prefetched AFTER current writes (always-correct; R14's trap was reading
// before writes). All per-iteration fma/exp/DPP trees unchanged -> results
// bit-identical to R13/R17.
__global__ __launch_bounds__(1024) void kern_scan(
    const float *__restrict__ normed, const float *__restrict__ pts,
    float *__restrict__ out, float *__restrict__ wglob)
{
  const int s = blockIdx.x;
  const int t = threadIdx.x;
  const int v = t >> 6;            // wave 0..15
  const int L = t & 63;

  __shared__ float2 dav[MDIM];     // 32 KB: (D, avacc), swizzled
  __shared__ float  barr[MDIM];    // 16 KB: b (phase-1 softmax weights)
  __shared__ float4 cstA[NIT + 4]; // (ux, uy, step1, Pk) per iter
  __shared__ int2   cstB[NIT + 4]; // (r0, c0) per iter
  __shared__ float  spfin;         // exact sum of Pk, k ascending
  __shared__ float  otred[16];

  // ---- init (all 16 waves; wave v owns grid rows 4v..4v+3) ----
  #pragma unroll
  for (int l = 0; l < 4; ++l) {
    const int r = 4 * v + l;
    const float bv = normed[s * MDIM + r * 64 + L];
    const int idx = swz(r, L);
    dav[idx]  = make_float2(__logf(bv), 0.0f);   // v0 = lnb
    barr[idx] = bv;
  }
  // per-iteration constants (bit-identical formulas, hoisted; R8-validated)
  if (t < NIT + 4) {
    const int kk = t < NIT ? t : (NIT - 1);
    const int idx = rand_idx(s * NIT + kk);
    const float2 p = ((const float2 *)pts)[s * NPTS + idx];
    const int rn = (int)floorf((p.y - 4.0f) * 0.125f + 0.5f);
    const int cn = (int)floorf((p.x - 4.0f) * 0.125f + 0.5f);
    int r0 = rn - 7; r0 = r0 < 0 ? 0 : (r0 > R0MAX ? R0MAX : r0);
    int c0 = cn - 7; c0 = c0 < 0 ? 0 : (c0 > R0MAX ? R0MAX : c0);
    const float kf    = (float)(kk + 1);
    const float step1 = 512.0f * __builtin_amdgcn_rsqf(kf);   // 0.1*lr/sqrt(k)
    const float Pk    = step1 * (0.01f * (101.0f - kf));
    cstA[t] = make_float4(p.x - (float)(8 * c0 + 4),
                          p.y - (float)(8 * r0 + 4), step1, Pk);
    cstB[t] = make_int2(r0, c0);
  }
  __syncthreads();

  const int rbase = L >> 4;        // 0..3 (window row within quad)
  const int cbase = L & 15;        // window col
  const float fc8 = (float)(8 * cbase);
  const float fr8 = (float)(8 * rbase);

  // ---- phase 1: 100-iter ASGD scan as 50 pair-steps, wave 0 only ----
  // (wave 1 lane 0 concurrently builds spfin with the identical add order)
  if (t == 64) {
    float SPa = 0.0f;
    for (int k = 0; k < NIT; ++k) SPa += cstA[k].w;
    spfin = SPa;
  }
  if (v == 0) {
    float A = 0.0f;
    // pair-0 state
    float4 cA  = cstA[0], cA2 = cstA[1];
    int2   cB  = cstB[0], cB2 = cstB[1];
    int j0 = swz(cB.x  + rbase, cB.y  + cbase);
    int j1 = swz(cB2.x + rbase, cB2.y + cbase);
    int dr = cB.x - cB2.x, dc = cB.y - cB2.y;
    int ovl = __builtin_amdgcn_readfirstlane(
        (int)(((unsigned)(dr + 15) < 31u) & ((unsigned)(dc + 15) < 31u)));
    // preload window kp (fresh: nothing written yet)
    float2 c0v = dav[j0      ]; float b0v = barr[j0      ];
    float2 c1v = dav[j0 + 256]; float b1v = barr[j0 + 256];
    float2 c2v = dav[j0 + 512]; float b2v = barr[j0 + 512];
    float2 c3v = dav[j0 + 768]; float b3v = barr[j0 + 768];
    float2 d0v, d1v, d2v, d3v; float g0v, g1v, g2v, g3v;
    if (!ovl) {                       // disjoint -> kp+1 readable now
      d0v = dav[j1      ]; g0v = barr[j1      ];
      d1v = dav[j1 + 256]; g1v = barr[j1 + 256];
      d2v = dav[j1 + 512]; g2v = barr[j1 + 512];
      d3v = dav[j1 + 768]; g3v = barr[j1 + 768];
    }

    for (int kp = 0; kp < NIT; kp += 2) {
      // next pair's constants + flags (consumed only in the tail)
      const float4 nA  = cstA[kp + 2], nA2 = cstA[kp + 3];
      const int2   nB  = cstB[kp + 2], nB2 = cstB[kp + 3];
      const int nj0 = swz(nB.x  + rbase, nB.y  + cbase);
      const int nj1 = swz(nB2.x + rbase, nB2.y + cbase);
      const int ndr = nB.x - nB2.x, ndc = nB.y - nB2.y;
      const int novl = __builtin_amdgcn_readfirstlane(
          (int)(((unsigned)(ndr + 15) < 31u) & ((unsigned)(ndc + 15) < 31u)));

      const float A2 = A + cA.z;     // iter kp+1's A (exact serial order)

      const float dx  = cA.x - fc8;  const float dxx  = dx  * dx;
      const float ty  = cA.y - fr8;
      const float dx2 = cA2.x - fc8; const float dxx2 = dx2 * dx2;
      const float ty2 = cA2.y - fr8;

      if (!ovl) {
        // ---- fused: two independent chains, interleaved (ILP) ----
        const float e0 = __expf(fmaf(fmaf(ty,           ty,           dxx ), -0.1f, fmaf(b0v, A,  c0v.x)));
        const float e1 = __expf(fmaf(fmaf(ty  - 32.0f,  ty  - 32.0f,  dxx ), -0.1f, fmaf(b1v, A,  c1v.x)));
        const float e2 = __expf(fmaf(fmaf(ty  - 64.0f,  ty  - 64.0f,  dxx ), -0.1f, fmaf(b2v, A,  c2v.x)));
        const float e3 = __expf(fmaf(fmaf(ty  - 96.0f,  ty  - 96.0f,  dxx ), -0.1f, fmaf(b3v, A,  c3v.x)));
        const float f0 = __expf(fmaf(fmaf(ty2,          ty2,          dxx2), -0.1f, fmaf(g0v, A2, d0v.x)));
        const float f1 = __expf(fmaf(fmaf(ty2 - 32.0f,  ty2 - 32.0f,  dxx2), -0.1f, fmaf(g1v, A2, d1v.x)));
        const float f2 = __expf(fmaf(fmaf(ty2 - 64.0f,  ty2 - 64.0f,  dxx2), -0.1f, fmaf(g2v, A2, d2v.x)));
        const float f3 = __expf(fmaf(fmaf(ty2 - 96.0f,  ty2 - 96.0f,  dxx2), -0.1f, fmaf(g3v, A2, d3v.x)));

        float S  = (e0 + e1) + (e2 + e3);
        float S2 = (f0 + f1) + (f2 + f3);
        waveSum2(S, S2);                           // bit-same trees as waveSum
        const float invS  = __builtin_amdgcn_rcpf(S);
        const float invS2 = __builtin_amdgcn_rcpf(S2);
        const float cD  = cA.z  * invS,  cAv  = cA.w  * invS;
        const float cD2 = cA2.z * invS2, cAv2 = cA2.w * invS2;

        c0v.x = fmaf(-cD, e0, c0v.x); c0v.y = fmaf(cAv, e0, c0v.y);
        c1v.x = fmaf(-cD, e1, c1v.x); c1v.y = fmaf(cAv, e1, c1v.y);
        c2v.x = fmaf(-cD, e2, c2v.x); c2v.y = fmaf(cAv, e2, c2v.y);
        c3v.x = fmaf(-cD, e3, c3v.x); c3v.y = fmaf(cAv, e3, c3v.y);
        d0v.x = fmaf(-cD2, f0, d0v.x); d0v.y = fmaf(cAv2, f0, d0v.y);
        d1v.x = fmaf(-cD2, f1, d1v.x); d1v.y = fmaf(cAv2, f1, d1v.y);
        d2v.x = fmaf(-cD2, f2, d2v.x); d2v.y = fmaf(cAv2, f2, d2v.y);
        d3v.x = fmaf(-cD2, f3, d3v.x); d3v.y = fmaf(cAv2, f3, d3v.y);
        dav[j0      ] = c0v; dav[j0 + 256] = c1v;
        dav[j0 + 512] = c2v; dav[j0 + 768] = c3v;
        dav[j1      ] = d0v; dav[j1 + 256] = d1v;
        dav[j1 + 512] = d2v; dav[j1 + 768] = d3v;
      } else {
        // ---- serial fallback: two R13-exact bodies ----
        const float e0 = __expf(fmaf(fmaf(ty,          ty,          dxx), -0.1f, fmaf(b0v, A, c0v.x)));
        const float e1 = __expf(fmaf(fmaf(ty - 32.0f, ty - 32.0f, dxx), -0.1f, fmaf(b1v, A, c1v.x)));
        const float e2 = __expf(fmaf(fmaf(ty - 64.0f, ty - 64.0f, dxx), -0.1f, fmaf(b2v, A, c2v.x)));
        const float e3 = __expf(fmaf(fmaf(ty - 96.0f, ty - 96.0f, dxx), -0.1f, fmaf(b3v, A, c3v.x)));
        const float S    = waveSum((e0 + e1) + (e2 + e3));
        const float invS = __builtin_amdgcn_rcpf(S);
        const float cD = cA.z * invS, cAv = cA.w * invS;
        c0v.x = fmaf(-cD, e0, c0v.x); c0v.y = fmaf(cAv, e0, c0v.y);
        c1v.x = fmaf(-cD, e1, c1v.x); c1v.y = fmaf(cAv, e1, c1v.y);
        c2v.x = fmaf(-cD, e2, c2v.x); c2v.y = fmaf(cAv, e2, c2v.y);
        c3v.x = fmaf(-cD, e3, c3v.x); c3v.y = fmaf(cAv, e3, c3v.y);
        dav[j0      ] = c0v; dav[j0 + 256] = c1v;
        dav[j0 + 512] = c2v; dav[j0 + 768] = c3v;

        // window kp+1 AFTER kp's writes (same-wave DS order -> fresh)
        d0v = dav[j1      ]; g0v = barr[j1      ];
        d1v = dav[j1 + 256]; g1v = barr[j1 + 256];
        d2v = dav[j1 + 512]; g2v = barr[j1 + 512];
        d3v = dav[j1 + 768]; g3v = barr[j1 + 768];

        const float f0 = __expf(fmaf(fmaf(ty2,          ty2,          dxx2), -0.1f, fmaf(g0v, A2, d0v.x)));
        const float f1 = __expf(fmaf(fmaf(ty2 - 32.0f, ty2 - 32.0f, dxx2), -0.1f, fmaf(g1v, A2, d1v.x)));
        const float f2 = __expf(fmaf(fmaf(ty2 - 64.0f, ty2 - 64.0f, dxx2), -0.1f, fmaf(g2v, A2, d2v.x)));
        const float f3 = __expf(fmaf(fmaf(ty2 - 96.0f, ty2 - 96.0f, dxx2), -0.1f, fmaf(g3v, A2, d3v.x)));
        const float S2    = waveSum((f0 + f1) + (f2 + f3));
        const float invS2 = __builtin_amdgcn_rcpf(S2);
        const float cD2 = cA2.z * invS2, cAv2 = cA2.w * invS2;
        d0v.x = fmaf(-cD2, f0, d0v.x); d0v.y = fmaf(cAv2, f0, d0v.y);
        d1v.x = fmaf(-cD2, f1, d1v.x); d1v.y = fmaf(cAv2, f1, d1v.y);
        d2v.x = fmaf(-cD2, f2, d2v.x); d2v.y = fmaf(cAv2, f2, d2v.y);
        d3v.x = fmaf(-cD2, f3, d3v.x); d3v.y = fmaf(cAv2, f3, d3v.y);
        dav[j1      ] = d0v; dav[j1 + 256] = d1v;
        dav[j1 + 512] = d2v; dav[j1 + 768] = d3v;
      }

      A = A2 + cA2.z;                // exact serial add order

      // ---- tail: rotate + prefetch next pair AFTER all writes ----
      cA = nA; cA2 = nA2; cB = nB; cB2 = nB2;
      j0 = nj0; j1 = nj1; ovl = novl;
      c0v = dav[j0      ]; b0v = barr[j0      ];
      c1v = dav[j0 + 256]; b1v = barr[j0 + 256];
      c2v = dav[j0 + 512]; b2v = barr[j0 + 512];
      c3v = dav[j0 + 768]; b3v = barr[j0 + 768];
      if (!ovl) {                     // next pair disjoint -> kp+3 readable now
        d0v = dav[j1      ]; g0v = barr[j1      ];
        d1v = dav[j1 + 256]; g1v = barr[j1 + 256];
        d2v = dav[j1 + 512]; g2v = barr[j1 + 512];
        d3v = dav[j1 + 768]; g3v = barr[j1 + 768];
      }
    }
  }
  __syncthreads();                               // dav final; spfin ready

  // ---- epilogue (ALL 16 waves, own slab): w[] -> global; ot partials ----
  {
    const float SP = spfin;
    float p_ot = 0.0f;
    #pragma unroll
    for (int l = 0; l < 4; ++l) {
      const int r   = 4 * v + l;
      const int idx = swz(r, L);
      const float2 cd = dav[idx];
      const float bb  = barr[idx];
      const float tt  = fmaf(bb, SP, -cd.y);     // 0.1*beta
      wglob[s * MDIM + r * 64 + L] = tt + __logf(bb);  // w = 0.1*beta + lnb
      p_ot = fmaf(bb, 10.0f * tt, p_ot);
    }
    p_ot = waveSum(p_ot);
    if (L == 0) otred[v] = p_ot;
  }
  __syncthreads();
  if (t == 0) {
    float ot = 0.0f;
    #pragma unroll
    for (int i = 0; i < 16; ++i) ot += otred[i];
    atomicAdd(&out[2], ot);
    // out[0] (loss): analytically exact 0; memset provides it.
  }
}

// ---------------- Kernel 2: windowed per-point wd, 8 slice-blocks/sample ----
// Block b: sample s = b>>3, slice q = b&7 (points 64q..64q+63). 16 waves,
// 4 points each (identical per-point math to R12's phase 2; only the
// cross-point summation tree regroups).
__global__ __launch_bounds__(1024) void kern_wd(
    const float *__restrict__ pts, const float *__restrict__ wglob,
    float *__restrict__ out)
{
  const int s = blockIdx.x >> 3;
  const int q = blockIdx.x & 7;
  const int t = threadIdx.x;
  const int v = t >> 6;            // wave 0..15
  const int L = t & 63;

  __shared__ float  wlds[MDIM];    // 16 KB: w[], swizzled as in kern_scan
  __shared__ float2 pts2[64];      // this slice's points
  __shared__ float  wdred[16];

  // stage w with the same parity swizzle so window reads are conflict-free
  #pragma unroll
  for (int l = 0; l < 4; ++l) {
    const int r = 4 * v + l;
    wlds[swz(r, L)] = wglob[s * MDIM + r * 64 + L];
  }
  if (t < 64) pts2[t] = ((const float2 *)pts)[s * NPTS + 64 * q + t];
  __syncthreads();

  const int rbase = L >> 4;        // 0..3 (window row within quad)
  const int cbase = L & 15;        // window col

  float pe[4], pq[4];
  #pragma unroll
  for (int i = 0; i < 4; ++i) {
    const int p = 4 * v + i;                   // point within slice
    const float2 pt = pts2[p];                 // LDS broadcast
    const float x = pt.x, y = pt.y;
    const int rn = (int)floorf((y - 4.0f) * 0.125f + 0.5f);
    const int cn = (int)floorf((x - 4.0f) * 0.125f + 0.5f);
    int r0 = rn - 7; r0 = r0 < 0 ? 0 : (r0 > R0MAX ? R0MAX : r0);
    int c0 = cn - 7; c0 = c0 < 0 ? 0 : (c0 > R0MAX ? R0MAX : c0);
    const int rl = r0 + rbase;
    const int cl = c0 + cbase;
    const int j0 = swz(rl, cl);

    const float dx  = x - (float)(8 * cl + 4);
    const float dxx = dx * dx;
    const float ty  = y - (float)(8 * rl + 4);
    float spe = 0.0f, spq = 0.0f;
    #pragma unroll
    for (int qq4 = 0; qq4 < 4; ++qq4) {
      const float wv = wlds[j0 + 256 * qq4];
      const float dy = ty - (float)(32 * qq4);
      const float qq = fmaf(dy, dy, dxx);
      const float e  = __expf(fmaf(qq, -0.1f, wv));
      spe += e;
      spq = fmaf(e, qq, spq);
    }
    pe[i] = spe; pq[i] = spq;
  }
  // 8 interleaved DPP sum chains
  #pragma unroll
  for (int i = 0; i < 4; ++i) { pe[i] += dpp_mv<0x111>(pe[i], 0.0f); pq[i] += dpp_mv<0x111>(pq[i], 0.0f); }
  #pragma unroll
  for (int i = 0; i < 4; ++i) { pe[i] += dpp_mv<0x112>(pe[i], 0.0f); pq[i] += dpp_mv<0x112>(pq[i], 0.0f); }
  #pragma unroll
  for (int i = 0; i < 4; ++i) { pe[i] += dpp_mv<0x114>(pe[i], 0.0f); pq[i] += dpp_mv<0x114>(pq[i], 0.0f); }
  #pragma unroll
  for (int i = 0; i < 4; ++i) { pe[i] += dpp_mv<0x118>(pe[i], 0.0f); pq[i] += dpp_mv<0x118>(pq[i], 0.0f); }
  #pragma unroll
  for (int i = 0; i < 4; ++i) { pe[i] += dpp_mv<0x142>(pe[i], 0.0f); pq[i] += dpp_mv<0x142>(pq[i], 0.0f); }
  #pragma unroll
  for (int i = 0; i < 4; ++i) { pe[i] += dpp_mv<0x143>(pe[i], 0.0f); pq[i] += dpp_mv<0x143>(pq[i], 0.0f); }

  float wdacc = 0.0f;
  #pragma unroll
  for (int i = 0; i < 4; ++i) {
    const float PE = __int_as_float(__builtin_amdgcn_readlane(__float_as_int(pe[i]), 63));
    const float PQ = __int_as_float(__builtin_amdgcn_readlane(__float_as_int(pq[i]), 63));
    wdacc = fmaf(PQ, __builtin_amdgcn_rcpf(PE), wdacc);
  }
  if (L == 0) wdred[v] = wdacc;
  __syncthreads();
  if (t == 0) {
    float wd = 0.0f;
    #pragma unroll
    for (int i = 0; i < 16; ++i) wd += wdred[i];
    atomicAdd(&out[1], wd * (1.0f / 512.0f));
  }
}

extern "C" void kernel_launch(void* const* d_in, const int* in_sizes, int n_in,
                              void* d_out, int out_size, void* d_ws, size_t ws_size,
                              hipStream_t stream)
{
  (void)in_sizes; (void)n_in; (void)out_size; (void)ws_size;
  const float *normed = (const float *)d_in[0];
  const float *pts    = (const float *)d_in[2];
  float *out   = (float *)d_out;
  float *wglob = (float *)d_ws;    // 16 * 4096 * 4 B = 256 KB of workspace

  hipMemsetAsync(out, 0, 3 * sizeof(float), stream);
  kern_scan<<<dim3(NSAMP),     dim3(1024), 0, stream>>>(normed, pts, out, wglob);
  kern_wd  <<<dim3(NSAMP * 8), dim3(1024), 0, stream>>>(pts, wglob, out);
}

// Round 7
// 84.774 us; speedup vs baseline: 1.4130x; 1.0161x over previous
//
#include <hip/hip_runtime.h>
#include <math.h>

// Problem constants (from reference)
#define NSAMP 16
#define NPTS  512
#define MDIM  4096     // 64*64 grid
#define NIT   100

// 16x16 window (rows rn-7..rn+8, cols cn-7..cn+8), 4 cells/lane for a wave.
// Support analysis (R4-R12-validated): first-visit pits displace the softmax
// mode ~3 cells; rim + mass tail needs +-6 cells -> 16x16 minimum safe.
#define R0MAX 48

// No-max softmax safety (R12-validated): z = v - 0.1*d^2 < 0 always and
// S >= e^-28 -> unshifted __expf neither overflows nor underflows S.

// parity swizzle: odd rows XOR col by 16 -> ~2 lanes/bank (R7: 75k -> 2k).
__device__ __forceinline__ int swz(int r, int c) {
  return r * 64 + (c ^ ((r & 1) << 4));
}

// ---------------- Threefry-2x32 (JAX-exact, partitionable path; R0-verified)
__device__ __forceinline__ void tf2x32(unsigned k0, unsigned k1,
                                       unsigned c0, unsigned c1,
                                       unsigned &o0, unsigned &o1)
{
  unsigned ks2 = k0 ^ k1 ^ 0x1BD11BDAu;
  unsigned x0 = c0 + k0, x1 = c1 + k1;
#define ROT(r) x0 += x1; x1 = (x1 << (r)) | (x1 >> (32 - (r))); x1 ^= x0;
#define G0 ROT(13) ROT(15) ROT(26) ROT(6)
#define G1 ROT(17) ROT(29) ROT(16) ROT(24)
  G0 x0 += k1;  x1 += ks2 + 1u;
  G1 x0 += ks2; x1 += k0  + 2u;
  G0 x0 += k0;  x1 += k1  + 3u;
  G1 x0 += k1;  x1 += ks2 + 4u;
  G0 x0 += ks2; x1 += k0  + 5u;
#undef G0
#undef G1
#undef ROT
  o0 = x0; o1 = x1;
}

__device__ __forceinline__ int rand_idx(int f)
{
  unsigned ka, kb, w0, w1;
  tf2x32(0u, 1u, 0u, 1u, ka, kb);            // split(key(1))[1] — folded
  tf2x32(ka, kb, 0u, (unsigned)f, w0, w1);   // random_bits elem f
  return (int)((w0 ^ w1) & 511u);
}

// ---------------- wave64 sum via DPP (R1-R12-verified pattern) --------------
template<int CTRL>
__device__ __forceinline__ float dpp_mv(float v, float id)
{
  return __int_as_float(__builtin_amdgcn_update_dpp(
      __float_as_int(id), __float_as_int(v), CTRL, 0xF, 0xF, false));
}

__device__ __forceinline__ float waveSum(float v)
{
  v += dpp_mv<0x111>(v, 0.0f);
  v += dpp_mv<0x112>(v, 0.0f);
  v += dpp_mv<0x114>(v, 0.0f);
  v += dpp_mv<0x118>(v, 0.0f);
  v += dpp_mv<0x142>(v, 0.0f);
  v += dpp_mv<0x143>(v, 0.0f);
  return __int_as_float(__builtin_amdgcn_readlane(__float_as_int(v), 63));
}

// ---------------- Kernel 1: scan (R13 serial body, packed state) -> w[] -----
// R20 = R17 with phase-1 state packed as float4 (D, avacc, b, 0) per cell.
// Rationale: R14/R15/R16/R19 all proved the scan's ~600 cy/iter is not one
// removable latency -- it's distributed in-order wait structure. The only
// remaining lever is op count: 12 LDS ops/iter (4x b64 + 4x b32 reads +
// 4x b64 writes) -> 8 (4x b128 read, 4x b128 write); the tail's dependent
// read cluster halves (4 loads not 8). Pure layout change: every arithmetic
// value/tree is untouched -> results bit-identical (absmax must stay
// exactly 2.533197e-06).
__global__ __launch_bounds__(1024) void kern_scan(
    const float *__restrict__ normed, const float *__restrict__ pts,
    float *__restrict__ out, float *__restrict__ wglob)
{
  const int s = blockIdx.x;
  const int t = threadIdx.x;
  const int v = t >> 6;            // wave 0..15
  const int L = t & 63;

  __shared__ float4 davb[MDIM];    // 64 KB: (D, avacc, b, 0), swizzled
  __shared__ float4 cstA[NIT + 4]; // (ux, uy, step1, Pk) per iter
  __shared__ int2   cstB[NIT + 4]; // (r0, c0) per iter
  __shared__ float  spfin;         // exact sum of Pk, k ascending
  __shared__ float  otred[16];

  // ---- init (all 16 waves; wave v owns grid rows 4v..4v+3) ----
  #pragma unroll
  for (int l = 0; l < 4; ++l) {
    const int r = 4 * v + l;
    const float bv = normed[s * MDIM + r * 64 + L];
    davb[swz(r, L)] = make_float4(__logf(bv), 0.0f, bv, 0.0f); // v0 = lnb
  }
  // per-iteration constants (bit-identical formulas, hoisted; R8-validated)
  if (t < NIT + 4) {
    const int kk = t < NIT ? t : (NIT - 1);
    const int idx = rand_idx(s * NIT + kk);
    const float2 p = ((const float2 *)pts)[s * NPTS + idx];
    const int rn = (int)floorf((p.y - 4.0f) * 0.125f + 0.5f);
    const int cn = (int)floorf((p.x - 4.0f) * 0.125f + 0.5f);
    int r0 = rn - 7; r0 = r0 < 0 ? 0 : (r0 > R0MAX ? R0MAX : r0);
    int c0 = cn - 7; c0 = c0 < 0 ? 0 : (c0 > R0MAX ? R0MAX : c0);
    const float kf    = (float)(kk + 1);
    const float step1 = 512.0f * __builtin_amdgcn_rsqf(kf);   // 0.1*lr/sqrt(k)
    const float Pk    = step1 * (0.01f * (101.0f - kf));
    cstA[t] = make_float4(p.x - (float)(8 * c0 + 4),
                          p.y - (float)(8 * r0 + 4), step1, Pk);
    cstB[t] = make_int2(r0, c0);
  }
  __syncthreads();

  const int rbase = L >> 4;        // 0..3 (window row within quad)
  const int cbase = L & 15;        // window col
  const float fc8 = (float)(8 * cbase);
  const float fr8 = (float)(8 * rbase);

  // ---- phase 1: 100-iter ASGD scan, wave 0 only (R13-exact arithmetic) ----
  // (wave 1 lane 0 concurrently builds spfin with the identical add order)
  if (t == 64) {
    float SPa = 0.0f;
    for (int k = 0; k < NIT; ++k) SPa += cstA[k].w;
    spfin = SPa;
  }
  if (v == 0) {
    float A = 0.0f;
    // preload iter 0: constants + state (R8 pipelined pattern)
    float4 cA = cstA[0];
    int2   cB = cstB[0];
    int j0 = swz(cB.x + rbase, cB.y + cbase);
    float4 c0v = davb[j0      ];   // (D, av, b, 0)
    float4 c1v = davb[j0 + 256];
    float4 c2v = davb[j0 + 512];
    float4 c3v = davb[j0 + 768];

    for (int k = 0; k < NIT; ++k) {
      // prefetch next-iter constants (independent; latency hidden under chain)
      const float4 cAn = cstA[k + 1];
      const int2   cBn = cstB[k + 1];

      const float dx  = cA.x - fc8;       // x - (8*(c0+cbase)+4)
      const float dxx = dx * dx;
      const float ty  = cA.y - fr8;       // dy_q = ty - 32q
      // unshifted exp: z < 0 always (R12-validated) -> no max reduction
      const float e0 = __expf(fmaf(fmaf(ty,          ty,          dxx), -0.1f, fmaf(c0v.z, A, c0v.x)));
      const float e1 = __expf(fmaf(fmaf(ty - 32.0f, ty - 32.0f, dxx), -0.1f, fmaf(c1v.z, A, c1v.x)));
      const float e2 = __expf(fmaf(fmaf(ty - 64.0f, ty - 64.0f, dxx), -0.1f, fmaf(c2v.z, A, c2v.x)));
      const float e3 = __expf(fmaf(fmaf(ty - 96.0f, ty - 96.0f, dxx), -0.1f, fmaf(c3v.z, A, c3v.x)));

      const float S    = waveSum((e0 + e1) + (e2 + e3));   // > 0
      const float invS = __builtin_amdgcn_rcpf(S);
      const float cD = cA.z * invS, cAv = cA.w * invS;

      c0v.x = fmaf(-cD, e0, c0v.x); c0v.y = fmaf(cAv, e0, c0v.y);
      c1v.x = fmaf(-cD, e1, c1v.x); c1v.y = fmaf(cAv, e1, c1v.y);
      c2v.x = fmaf(-cD, e2, c2v.x); c2v.y = fmaf(cAv, e2, c2v.y);
      c3v.x = fmaf(-cD, e3, c3v.x); c3v.y = fmaf(cAv, e3, c3v.y);
      davb[j0      ] = c0v;          // b (.z) written back unchanged
      davb[j0 + 256] = c1v;
      davb[j0 + 512] = c2v;
      davb[j0 + 768] = c3v;

      A += cA.z;

      // rotate + issue next-iter state reads AFTER the writes (same-wave DS
      // ordering guarantees RAW; latency overlaps loop-back + z-prep)
      cA = cAn; cB = cBn;
      j0 = swz(cB.x + rbase, cB.y + cbase);
      c0v = davb[j0      ];
      c1v = davb[j0 + 256];
      c2v = davb[j0 + 512];
      c3v = davb[j0 + 768];
    }
  }
  __syncthreads();                               // davb final; spfin ready

  // ---- epilogue (ALL 16 waves, own slab): w[] -> global; ot partials ----
  {
    const float SP = spfin;
    float p_ot = 0.0f;
    #pragma unroll
    for (int l = 0; l < 4; ++l) {
      const int r   = 4 * v + l;
      const float4 cd = davb[swz(r, L)];
      const float bb  = cd.z;
      const float tt  = fmaf(bb, SP, -cd.y);     // 0.1*beta
      wglob[s * MDIM + r * 64 + L] = tt + __logf(bb);  // w = 0.1*beta + lnb
      p_ot = fmaf(bb, 10.0f * tt, p_ot);
    }
    p_ot = waveSum(p_ot);
    if (L == 0) otred[v] = p_ot;
  }
  __syncthreads();
  if (t == 0) {
    float ot = 0.0f;
    #pragma unroll
    for (int i = 0; i < 16; ++i) ot += otred[i];
    atomicAdd(&out[2], ot);
    // out[0] (loss): analytically exact 0; memset provides it.
  }
}

// ---------------- Kernel 2: windowed per-point wd, 8 slice-blocks/sample ----
// Block b: sample s = b>>3, slice q = b&7 (points 64q..64q+63). 16 waves,
// 4 points each (identical per-point math to R12's phase 2; only the
// cross-point summation tree regroups). R20: staging vectorized (float4
// global load + b128 LDS write; 4-aligned col groups stay contiguous under
// the parity swizzle).
__global__ __launch_bounds__(1024) void kern_wd(
    const float *__restrict__ pts, const float *__restrict__ wglob,
    float *__restrict__ out)
{
  const int s = blockIdx.x >> 3;
  const int q = blockIdx.x & 7;
  const int t = threadIdx.x;
  const int v = t >> 6;            // wave 0..15
  const int L = t & 63;

  __shared__ float  wlds[MDIM];    // 16 KB: w[], swizzled as in kern_scan
  __shared__ float2 pts2[64];      // this slice's points
  __shared__ float  wdred[16];

  // stage w with the same parity swizzle (vectorized: thread t -> row t>>4,
  // cols 4*(t&15)..+3; xor-by-16 maps 4-aligned groups contiguously)
  {
    const int r  = t >> 4;
    const int c4 = (t & 15) << 2;
    const float4 w4 = ((const float4 *)(wglob + s * MDIM + r * 64))[t & 15];
    *(float4 *)&wlds[swz(r, c4)] = w4;
  }
  if (t < 64) pts2[t] = ((const float2 *)pts)[s * NPTS + 64 * q + t];
  __syncthreads();

  const int rbase = L >> 4;        // 0..3 (window row within quad)
  const int cbase = L & 15;        // window col

  float pe[4], pq[4];
  #pragma unroll
  for (int i = 0; i < 4; ++i) {
    const int p = 4 * v + i;                   // point within slice
    const float2 pt = pts2[p];                 // LDS broadcast
    const float x = pt.x, y = pt.y;
    const int rn = (int)floorf((y - 4.0f) * 0.125f + 0.5f);
    const int cn = (int)floorf((x - 4.0f) * 0.125f + 0.5f);
    int r0 = rn - 7; r0 = r0 < 0 ? 0 : (r0 > R0MAX ? R0MAX : r0);
    int c0 = cn - 7; c0 = c0 < 0 ? 0 : (c0 > R0MAX ? R0MAX : c0);
    const int rl = r0 + rbase;
    const int cl = c0 + cbase;
    const int j0 = swz(rl, cl);

    const float dx  = x - (float)(8 * cl + 4);
    const float dxx = dx * dx;
    const float ty  = y - (float)(8 * rl + 4);
    float spe = 0.0f, spq = 0.0f;
    #pragma unroll
    for (int qq4 = 0; qq4 < 4; ++qq4) {
      const float wv = wlds[j0 + 256 * qq4];
      const float dy = ty - (float)(32 * qq4);
      const float qq = fmaf(dy, dy, dxx);
      const float e  = __expf(fmaf(qq, -0.1f, wv));
      spe += e;
      spq = fmaf(e, qq, spq);
    }
    pe[i] = spe; pq[i] = spq;
  }
  // 8 interleaved DPP sum chains
  #pragma unroll
  for (int i = 0; i < 4; ++i) { pe[i] += dpp_mv<0x111>(pe[i], 0.0f); pq[i] += dpp_mv<0x111>(pq[i], 0.0f); }
  #pragma unroll
  for (int i = 0; i < 4; ++i) { pe[i] += dpp_mv<0x112>(pe[i], 0.0f); pq[i] += dpp_mv<0x112>(pq[i], 0.0f); }
  #pragma unroll
  for (int i = 0; i < 4; ++i) { pe[i] += dpp_mv<0x114>(pe[i], 0.0f); pq[i] += dpp_mv<0x114>(pq[i], 0.0f); }
  #pragma unroll
  for (int i = 0; i < 4; ++i) { pe[i] += dpp_mv<0x118>(pe[i], 0.0f); pq[i] += dpp_mv<0x118>(pq[i], 0.0f); }
  #pragma unroll
  for (int i = 0; i < 4; ++i) { pe[i] += dpp_mv<0x142>(pe[i], 0.0f); pq[i] += dpp_mv<0x142>(pq[i], 0.0f); }
  #pragma unroll
  for (int i = 0; i < 4; ++i) { pe[i] += dpp_mv<0x143>(pe[i], 0.0f); pq[i] += dpp_mv<0x143>(pq[i], 0.0f); }

  float wdacc = 0.0f;
  #pragma unroll
  for (int i = 0; i < 4; ++i) {
    const float PE = __int_as_float(__builtin_amdgcn_readlane(__float_as_int(pe[i]), 63));
    const float PQ = __int_as_float(__builtin_amdgcn_readlane(__float_as_int(pq[i]), 63));
    wdacc = fmaf(PQ, __builtin_amdgcn_rcpf(PE), wdacc);
  }
  if (L == 0) wdred[v] = wdacc;
  __syncthreads();
  if (t == 0) {
    float wd = 0.0f;
    #pragma unroll
    for (int i = 0; i < 16; ++i) wd += wdred[i];
    atomicAdd(&out[1], wd * (1.0f / 512.0f));
  }
}

extern "C" void kernel_launch(void* const* d_in, const int* in_sizes, int n_in,
                              void* d_out, int out_size, void* d_ws, size_t ws_size,
                              hipStream_t stream)
{
  (void)in_sizes; (void)n_in; (void)out_size; (void)ws_size;
  const float *normed = (const float *)d_in[0];
  const float *pts    = (const float *)d_in[2];
  float *out   = (float *)d_out;
  float *wglob = (float *)d_ws;    // 16 * 4096 * 4 B = 256 KB of workspace

  hipMemsetAsync(out, 0, 3 * sizeof(float), stream);
  kern_scan<<<dim3(NSAMP),     dim3(1024), 0, stream>>>(normed, pts, out, wglob);
  kern_wd  <<<dim3(NSAMP * 8), dim3(1024), 0, stream>>>(pts, wglob, out);
}